// Round 1
// baseline (1017.861 us; speedup 1.0000x reference)
//
#include <hip/hip_runtime.h>
#include <math.h>

#define N_ROWS 12544   // 16*28*28
#define C_DIM  1536
#define M_ROWS 16384
#define BATCH  16

typedef __bf16 bf16;
typedef __bf16 bf16x8 __attribute__((ext_vector_type(8)));
typedef float  f32x4  __attribute__((ext_vector_type(4)));

// order-preserving float->uint key (handles negatives safely for atomicMin)
__device__ __forceinline__ unsigned fkey(float f) {
  unsigned u = __float_as_uint(f);
  return (u & 0x80000000u) ? ~u : (u | 0x80000000u);
}
__device__ __forceinline__ float funkey(unsigned k) {
  unsigned u = (k & 0x80000000u) ? (k ^ 0x80000000u) : ~k;
  return __uint_as_float(u);
}

__device__ __forceinline__ void gl_lds16(const void* g, void* l) {
  __builtin_amdgcn_global_load_lds(
      (__attribute__((address_space(1))) void*)(g),
      (__attribute__((address_space(3))) void*)(l), 16, 0, 0);
}

// ---------------- Kernel A: build bf16 feature rows + x_sq ----------------
// feats[n][c]: c<512 from feat2[b][c][y][x]; c>=512 bilinear-up feat3 14->28.
__global__ void prep_feats(const float* __restrict__ feat2,
                           const float* __restrict__ feat3,
                           bf16* __restrict__ feats,
                           float* __restrict__ xsq) {
  const int n = blockIdx.x;
  const int t = threadIdx.x;
  const int b = n / 784;
  const int rem = n % 784;
  const int y = rem / 28, x = rem % 28;
  // half-pixel src coords for 28 -> 14 (scale 0.5): src = 0.5*dst - 0.25
  const float sy = 0.5f * y - 0.25f;
  const float sx = 0.5f * x - 0.25f;
  const int y0 = (int)floorf(sy); const float fy = sy - (float)y0;
  const int x0 = (int)floorf(sx); const float fx = sx - (float)x0;
  const int y0c = max(y0, 0), y1c = min(y0 + 1, 13);
  const int x0c = max(x0, 0), x1c = min(x0 + 1, 13);
  const float w00 = (1.f-fy)*(1.f-fx), w01 = (1.f-fy)*fx;
  const float w10 = fy*(1.f-fx),       w11 = fy*fx;

  float ssq = 0.f;
  bf16* orow = feats + (size_t)n * C_DIM;
  for (int c = t; c < C_DIM; c += 256) {
    float v;
    if (c < 512) {
      v = feat2[(((size_t)b * 512 + c) * 28 + y) * 28 + x];
    } else {
      const float* f3 = feat3 + ((size_t)b * 1024 + (c - 512)) * 196;
      v = w00 * f3[y0c*14 + x0c] + w01 * f3[y0c*14 + x1c]
        + w10 * f3[y1c*14 + x0c] + w11 * f3[y1c*14 + x1c];
    }
    bf16 hb = (bf16)v;
    orow[c] = hb;
    float vb = (float)hb;
    ssq += vb * vb;
  }
  __shared__ float sred[4];
  for (int off = 32; off > 0; off >>= 1) ssq += __shfl_down(ssq, off, 64);
  if ((t & 63) == 0) sred[t >> 6] = ssq;
  __syncthreads();
  if (t == 0) xsq[n] = sred[0] + sred[1] + sred[2] + sred[3];
}

// ---------------- Kernel B: bf16 memory bank + m_sq ----------------
__global__ void prep_mb(const float* __restrict__ mb,
                        bf16* __restrict__ mbb,
                        float* __restrict__ msq) {
  const int j = blockIdx.x, t = threadIdx.x;
  const float* in = mb + (size_t)j * C_DIM;
  bf16* out = mbb + (size_t)j * C_DIM;
  float ssq = 0.f;
  for (int c = t; c < C_DIM; c += 256) {
    bf16 hb = (bf16)in[c];
    out[c] = hb;
    float vb = (float)hb;
    ssq += vb * vb;
  }
  __shared__ float sred[4];
  for (int off = 32; off > 0; off >>= 1) ssq += __shfl_down(ssq, off, 64);
  if ((t & 63) == 0) sred[t >> 6] = ssq;
  __syncthreads();
  if (t == 0) msq[j] = sred[0] + sred[1] + sred[2] + sred[3];
}

// ---------------- init min buffer ----------------
__global__ void init_min(unsigned* __restrict__ dmin) {
  int i = blockIdx.x * 256 + threadIdx.x;
  if (i < N_ROWS) dmin[i] = 0xFFFFFFFFu;
}

// ---------------- Kernel C: bf16 MFMA GEMM + fused min over M ----------------
// Block: 256 thr (4 waves), tile 128(rows N) x 128(cols M), BK=32.
// Tracks min_j (m_sq[j] - 2*dot(x_i, m_j)); x_sq added in finalize.
__global__ void gemm_min(const bf16* __restrict__ X, const bf16* __restrict__ Mb,
                         const float* __restrict__ msq,
                         unsigned* __restrict__ dmin) {
  __shared__ bf16 As[128 * 32];
  __shared__ bf16 Bs[128 * 32];
  __shared__ unsigned smin[128];
  const int t = threadIdx.x;
  const int mtile = blockIdx.x;   // 0..127 over M
  const int ntile = blockIdx.y;   // 0..97  over N
  const int lane = t & 63, wave = t >> 6;
  const int wm = wave >> 1, wn = wave & 1;
  if (t < 128) smin[t] = 0xFFFFFFFFu;

  const int row0 = ntile * 128;
  const int col0 = mtile * 128;
  const size_t lda = C_DIM;
  // staging map: thread t loads 16B for row (t>>2), k-offset (t&3)*8 elems
  const bf16* ga = X  + (size_t)(row0 + (t >> 2)) * lda + (size_t)(t & 3) * 8;
  const bf16* gb = Mb + (size_t)(col0 + (t >> 2)) * lda + (size_t)(t & 3) * 8;
  bf16* la = As + t * 8;   // = (t>>2)*32 + (t&3)*8 : row-major [128][32]
  bf16* lb = Bs + t * 8;

  f32x4 acc[4][4];
  const f32x4 zero = {0.f, 0.f, 0.f, 0.f};
#pragma unroll
  for (int mi = 0; mi < 4; mi++)
#pragma unroll
    for (int ni = 0; ni < 4; ni++) acc[mi][ni] = zero;

  const int quad = lane >> 4, l16 = lane & 15;
  const bf16* arow = As + (wm*64 + l16) * 32 + quad * 8;
  const bf16* brow = Bs + (wn*64 + l16) * 32 + quad * 8;

  for (int k0 = 0; k0 < C_DIM; k0 += 32) {
    __syncthreads();
    gl_lds16(ga + k0,            la);
    gl_lds16(ga + 64*lda + k0,   la + 64*32);
    gl_lds16(gb + k0,            lb);
    gl_lds16(gb + 64*lda + k0,   lb + 64*32);
    __syncthreads();
    bf16x8 afrag[4], bfrag[4];
#pragma unroll
    for (int mi = 0; mi < 4; mi++)
      afrag[mi] = *(const bf16x8*)(arow + mi*16*32);
#pragma unroll
    for (int ni = 0; ni < 4; ni++)
      bfrag[ni] = *(const bf16x8*)(brow + ni*16*32);
#pragma unroll
    for (int mi = 0; mi < 4; mi++)
#pragma unroll
      for (int ni = 0; ni < 4; ni++)
        acc[mi][ni] = __builtin_amdgcn_mfma_f32_16x16x32_bf16(
            afrag[mi], bfrag[ni], acc[mi][ni], 0, 0, 0);
  }

  // epilogue: v = m_sq[j] - 2*dot ; min over cols of this block's 128-wide slab
  float msql[4];
#pragma unroll
  for (int ni = 0; ni < 4; ni++)
    msql[ni] = msq[col0 + wn*64 + ni*16 + l16];

#pragma unroll
  for (int mi = 0; mi < 4; mi++) {
#pragma unroll
    for (int r = 0; r < 4; r++) {
      float v = msql[0] - 2.f * acc[mi][0][r];
#pragma unroll
      for (int ni = 1; ni < 4; ni++)
        v = fminf(v, msql[ni] - 2.f * acc[mi][ni][r]);
      // min across the 16 col-lanes of the quad
      v = fminf(v, __shfl_xor(v, 1, 64));
      v = fminf(v, __shfl_xor(v, 2, 64));
      v = fminf(v, __shfl_xor(v, 4, 64));
      v = fminf(v, __shfl_xor(v, 8, 64));
      if (l16 == 0) {
        int lrow = wm*64 + mi*16 + quad*4 + r;  // C/D: row = quad*4 + reg
        atomicMin(&smin[lrow], fkey(v));
      }
    }
  }
  __syncthreads();
  if (t < 128) atomicMin(&dmin[row0 + t], smin[t]);
}

// ---------------- Kernel D: sqrt + 28->224 bilinear + per-image max ----------
__global__ void finalize(const unsigned* __restrict__ dmin,
                         const float* __restrict__ xsq,
                         float* __restrict__ out) {
  const int b = blockIdx.x, t = threadIdx.x;
  __shared__ float smap[784];
  __shared__ float sred[4];
  for (int i = t; i < 784; i += 256) {
    float d2 = xsq[b*784 + i] + funkey(dmin[b*784 + i]);
    smap[i] = sqrtf(fmaxf(d2, 0.f));
  }
  __syncthreads();
  float* omap = out + (size_t)b * 50176;
  float tmax = -1e30f;
  for (int p = t; p < 50176; p += 256) {
    const int Y = p / 224, Xp = p % 224;
    const float sy = Y * 0.125f - 0.4375f;   // (dst+0.5)/8 - 0.5
    const float sx = Xp * 0.125f - 0.4375f;
    const int y0 = (int)floorf(sy); const float fy = sy - (float)y0;
    const int x0 = (int)floorf(sx); const float fx = sx - (float)x0;
    const int y0c = max(y0, 0), y1c = min(y0 + 1, 27);
    const int x0c = max(x0, 0), x1c = min(x0 + 1, 27);
    float v = (1.f-fy)*((1.f-fx)*smap[y0c*28+x0c] + fx*smap[y0c*28+x1c])
            +      fy *((1.f-fx)*smap[y1c*28+x0c] + fx*smap[y1c*28+x1c]);
    omap[p] = v;
    tmax = fmaxf(tmax, v);
  }
  for (int off = 32; off > 0; off >>= 1)
    tmax = fmaxf(tmax, __shfl_down(tmax, off, 64));
  if ((t & 63) == 0) sred[t >> 6] = tmax;
  __syncthreads();
  if (t == 0)
    out[802816 + b] = fmaxf(fmaxf(sred[0], sred[1]), fmaxf(sred[2], sred[3]));
}

extern "C" void kernel_launch(void* const* d_in, const int* in_sizes, int n_in,
                              void* d_out, int out_size, void* d_ws, size_t ws_size,
                              hipStream_t stream) {
  const float* feat2 = (const float*)d_in[0];  // [16,512,28,28]
  const float* feat3 = (const float*)d_in[1];  // [16,1024,14,14]
  const float* mb    = (const float*)d_in[2];  // [16384,1536]
  char* ws = (char*)d_ws;
  // layout (all 16B-aligned):
  bf16*     feats = (bf16*)ws;                         // 12544*1536*2 = 38,535,168
  bf16*     mbb   = (bf16*)(ws + 38535168);            // 16384*1536*2 = 50,331,648
  float*    xsq   = (float*)(ws + 88866816);           // 12544*4
  float*    msq   = (float*)(ws + 88916992);           // 16384*4
  unsigned* dmin  = (unsigned*)(ws + 88982528);        // 12544*4
  float* out = (float*)d_out;

  prep_feats<<<N_ROWS, 256, 0, stream>>>(feat2, feat3, feats, xsq);
  prep_mb<<<M_ROWS, 256, 0, stream>>>(mb, mbb, msq);
  init_min<<<(N_ROWS + 255) / 256, 256, 0, stream>>>(dmin);
  gemm_min<<<dim3(128, 98), 256, 0, stream>>>(feats, mbb, msq, dmin);
  finalize<<<BATCH, 256, 0, stream>>>(dmin, xsq, out);
}